// Round 3
// baseline (12529.202 us; speedup 1.0000x reference)
//
#include <hip/hip_runtime.h>

#define TSTEPS 512
#define DK 512       // D == H == 512
#define NC 2048      // 4H
#define NWG 128      // recurrent workgroups
#define WGT 256

typedef unsigned int u32;
typedef unsigned short u16;

static __device__ __forceinline__ float bf2f(u16 u) {
    return __uint_as_float(((u32)u) << 16);
}
static __device__ __forceinline__ u16 f2bf(float f) {
    u32 u = __float_as_uint(f);
    u += 0x7fffu + ((u >> 16) & 1u);
    return (u16)(u >> 16);
}
static __device__ __forceinline__ float sigmoidf_(float x) { return 1.0f / (1.0f + __expf(-x)); }
static __device__ __forceinline__ float tanhf_(float x)    { return 1.0f - 2.0f / (__expf(2.0f * x) + 1.0f); }

// ---------------------------------------------------------------------------
// K1 (new): transposed-output GEMM.
// xwt[(t*NC + c)*64 + b] = bf16( sum_k x[b][t][k]*Wx[k][c] + bias[c] )
// Grid (512 t, 32 c-tiles); block 256. Per block: 64c x 64b, K=512.
// ---------------------------------------------------------------------------
__global__ __launch_bounds__(256)
void gemm_xwt(const float* __restrict__ x, const float* __restrict__ Wx,
              const float* __restrict__ bias, u16* __restrict__ xwt) {
    __shared__ float As[16][64];   // [k][c]
    __shared__ float Bs[16][68];   // [k][b], +4 pad
    const int tid = threadIdx.x;
    const int t   = blockIdx.x;
    const int c0  = blockIdx.y * 64;

    const int lk  = tid >> 4;          // Wx: k 0..15
    const int lc  = (tid & 15) << 2;   // Wx: c 0..60
    const int lb  = tid >> 2;          // x:  b 0..63
    const int lkx = (tid & 3) << 2;    // x:  k 0,4,8,12

    const int tc  = tid & 15;          // c-frag
    const int tb  = tid >> 4;          // b-frag

    float acc[4][4] = {};   // [c][b]

    for (int k0 = 0; k0 < DK; k0 += 16) {
        const float4 av = *(const float4*)(Wx + (size_t)(k0 + lk) * NC + c0 + lc);
        const float4 bv = *(const float4*)(x + ((size_t)lb * TSTEPS + t) * DK + k0 + lkx);
        __syncthreads();
        *(float4*)&As[lk][lc] = av;
        Bs[lkx + 0][lb] = bv.x;
        Bs[lkx + 1][lb] = bv.y;
        Bs[lkx + 2][lb] = bv.z;
        Bs[lkx + 3][lb] = bv.w;
        __syncthreads();
        #pragma unroll
        for (int k = 0; k < 16; ++k) {
            float a4[4], b4[4];
            *(float4*)a4 = *(const float4*)&As[k][tc << 2];
            *(float4*)b4 = *(const float4*)&Bs[k][tb << 2];
            #pragma unroll
            for (int i = 0; i < 4; ++i)
                #pragma unroll
                for (int j = 0; j < 4; ++j)
                    acc[i][j] += a4[i] * b4[j];
        }
    }

    const float4 bias4 = *(const float4*)(bias + c0 + (tc << 2));
    const float bi[4] = {bias4.x, bias4.y, bias4.z, bias4.w};
    #pragma unroll
    for (int i = 0; i < 4; ++i) {
        const size_t row = (size_t)t * NC + c0 + (tc << 2) + i;
        ushort4 s;
        s.x = f2bf(acc[i][0] + bi[i]);
        s.y = f2bf(acc[i][1] + bi[i]);
        s.z = f2bf(acc[i][2] + bi[i]);
        s.w = f2bf(acc[i][3] + bi[i]);
        *(ushort4*)(xwt + row * 64 + (tb << 2)) = s;
    }
}

// ---------------------------------------------------------------------------
// Fallback pair (only if ws too small): round-1/2 kernels, [b][t][c] layout.
// ---------------------------------------------------------------------------
__global__ __launch_bounds__(256)
void gemm_xw(const float* __restrict__ x, const float* __restrict__ Wx,
             const float* __restrict__ bias, u16* __restrict__ xw_out) {
    __shared__ float As[16][68];
    __shared__ float Bs[16][64];
    const int tid  = threadIdx.x;
    const int tx   = tid & 15;
    const int ty   = tid >> 4;
    const int row0 = blockIdx.x * 64;
    const int col0 = blockIdx.y * 64;
    const int ar = tid >> 2;
    const int ak = (tid & 3) << 2;
    const int bk = tid >> 4;
    const int bc = (tid & 15) << 2;
    float acc[4][4] = {};
    for (int k0 = 0; k0 < DK; k0 += 16) {
        const float4 av = *(const float4*)(x  + (size_t)(row0 + ar) * DK + k0 + ak);
        const float4 bv = *(const float4*)(Wx + (size_t)(k0 + bk) * NC + col0 + bc);
        __syncthreads();
        As[ak + 0][ar] = av.x; As[ak + 1][ar] = av.y;
        As[ak + 2][ar] = av.z; As[ak + 3][ar] = av.w;
        *(float4*)&Bs[bk][bc] = bv;
        __syncthreads();
        #pragma unroll
        for (int k = 0; k < 16; ++k) {
            float a4[4], b4[4];
            *(float4*)a4 = *(const float4*)&As[k][ty << 2];
            *(float4*)b4 = *(const float4*)&Bs[k][tx << 2];
            #pragma unroll
            for (int i = 0; i < 4; ++i)
                #pragma unroll
                for (int j = 0; j < 4; ++j)
                    acc[i][j] += a4[i] * b4[j];
        }
    }
    #pragma unroll
    for (int i = 0; i < 4; ++i) {
        const size_t row = (size_t)row0 + (ty << 2) + i;
        const int    col = col0 + (tx << 2);
        ushort4 s;
        s.x = f2bf(acc[i][0] + bias[col + 0]);
        s.y = f2bf(acc[i][1] + bias[col + 1]);
        s.z = f2bf(acc[i][2] + bias[col + 2]);
        s.w = f2bf(acc[i][3] + bias[col + 3]);
        *(ushort4*)(xw_out + row * NC + col) = s;
    }
}

__global__ __launch_bounds__(512)
void lstm_rec_old(const u16* __restrict__ xw, const float* __restrict__ Wh,
                  const float* __restrict__ h0, float* __restrict__ out) {
    __shared__ float h_s[DK];
    __shared__ float c_s[DK];
    __shared__ float a_s[NC];
    const int b   = blockIdx.x;
    const int tid = threadIdx.x;
    const int q   = tid << 2;
    h_s[tid] = h0[(size_t)b * DK + tid];
    c_s[tid] = 0.0f;
    __syncthreads();
    for (int t = 0; t < TSTEPS; ++t) {
        const size_t rowoff = ((size_t)b * TSTEPS + t) * NC;
        const ushort4 xv = *(const ushort4*)(xw + rowoff + q);
        float4 acc;
        acc.x = bf2f(xv.x); acc.y = bf2f(xv.y); acc.z = bf2f(xv.z); acc.w = bf2f(xv.w);
        const float* wp = Wh + q;
        #pragma unroll 4
        for (int k = 0; k < DK; k += 4) {
            const float4 hk = *(const float4*)&h_s[k];
            const float4 w0 = *(const float4*)(wp + (size_t)(k + 0) * NC);
            const float4 w1 = *(const float4*)(wp + (size_t)(k + 1) * NC);
            const float4 w2 = *(const float4*)(wp + (size_t)(k + 2) * NC);
            const float4 w3 = *(const float4*)(wp + (size_t)(k + 3) * NC);
            acc.x += hk.x * w0.x + hk.y * w1.x + hk.z * w2.x + hk.w * w3.x;
            acc.y += hk.x * w0.y + hk.y * w1.y + hk.z * w2.y + hk.w * w3.y;
            acc.z += hk.x * w0.z + hk.y * w1.z + hk.z * w2.z + hk.w * w3.z;
            acc.w += hk.x * w0.w + hk.y * w1.w + hk.z * w2.w + hk.w * w3.w;
        }
        *(float4*)&a_s[q] = acc;
        __syncthreads();
        const float ig = sigmoidf_(a_s[tid]);
        const float fg = sigmoidf_(a_s[DK + tid]);
        const float og = sigmoidf_(a_s[2 * DK + tid]);
        const float gg = tanhf_(a_s[3 * DK + tid]);
        const float c  = fg * c_s[tid] + ig * gg;
        const float h  = og * tanhf_(c);
        c_s[tid] = c;
        h_s[tid] = h;
        out[((size_t)b * TSTEPS + t) * DK + tid] = h;
        __syncthreads();
    }
}

// ---------------------------------------------------------------------------
__global__ void init_cnt(u32* cnt) {
    const int i = threadIdx.x;
    if (i < 8) cnt[i * 16] = 0u;
}

// ---------------------------------------------------------------------------
// K2 (v3): single sync per step, relaxed polling, pipelined h staging.
// 128 WGs x 256 thr; WG g owns units 4g..4g+3 (wave wv -> unit 4g+wv);
// lane = batch. Wh slice fp32 in LDS (32 KB). h exchanged via global
// h_buf[t&1] in [u][b] layout (write-through relaxed atomic stores); 8
// counters (16 WGs each) RELEASE-incremented once per WG per step; waiters
// poll all 8 with RELAXED loads (no cache inv per poll), then one acquire
// fence. h staged to LDS in 8x16KB chunks, double-buffered, reg-prefetch
// of chunk c+1 overlapping compute of chunk c.
// ---------------------------------------------------------------------------
__global__ __launch_bounds__(WGT, 1)
void lstm_rec3(const u16* __restrict__ xwt, const float* __restrict__ Wh,
               const float* __restrict__ h0, float* __restrict__ out,
               float* __restrict__ h_buf, u32* __restrict__ cnt) {
    __shared__ float wh_s[4][4][DK];     // [unit][gate][k]  32 KB
    __shared__ float h_s[2][64 * 64];    // [buf][k'][b]     32 KB dbuf
    const int tid = threadIdx.x;
    const int b   = tid & 63;
    const int wv  = __builtin_amdgcn_readfirstlane(tid >> 6);
    const int g   = blockIdx.x;
    const int u   = 4 * g + wv;
    const int grp = g >> 4;              // 8 groups of 16 WGs

    // Preload Wh slice, float4 over the 4 units: wh_s[i][j][k] = Wh[k][j*512+4g+i]
    for (int m = 0; m < 8; ++m) {
        const int idx = tid + 256 * m;   // 0..2047
        const int k   = idx >> 2;
        const int j   = idx & 3;
        const float4 v = *(const float4*)(Wh + (size_t)k * NC + j * 512 + 4 * g);
        wh_s[0][j][k] = v.x; wh_s[1][j][k] = v.y;
        wh_s[2][j][k] = v.z; wh_s[3][j][k] = v.w;
    }

    // publish h0 (transposed [u][b], write-through)
    __hip_atomic_store(&h_buf[u * 64 + b], h0[(size_t)b * DK + u],
                       __ATOMIC_RELAXED, __HIP_MEMORY_SCOPE_AGENT);
    float creg = 0.0f;
    __syncthreads();
    if (tid == 0)
        __hip_atomic_fetch_add(&cnt[grp * 16], 1u, __ATOMIC_RELEASE, __HIP_MEMORY_SCOPE_AGENT);

    for (int t = 0; t < TSTEPS; ++t) {
        // xwt prefetch: coalesced (128 B per gate-col row); in flight during spin
        const u16* xp = xwt + (size_t)t * NC * 64;
        const u16 x0 = xp[(size_t)(u       ) * 64 + b];
        const u16 x1 = xp[(size_t)(u +  512) * 64 + b];
        const u16 x2 = xp[(size_t)(u + 1024) * 64 + b];
        const u16 x3 = xp[(size_t)(u + 1536) * 64 + b];

        // ---- wait for h(t): relaxed polls, one acquire fence after ----
        const u32 target = 16u * (u32)(t + 1);
        if (tid < 64) {
            bool ok;
            do {
                u32 v = 0xFFFFFFFFu;
                if (tid < 8)
                    v = __hip_atomic_load(&cnt[tid * 16], __ATOMIC_RELAXED,
                                          __HIP_MEMORY_SCOPE_AGENT);
                ok = __all((int)(v >= target));
                if (!ok) __builtin_amdgcn_s_sleep(2);
            } while (!ok);
        }
        __syncthreads();
        __builtin_amdgcn_fence(__ATOMIC_ACQUIRE, "agent");

        const float* hb = h_buf + (size_t)(t & 1) * (DK * 64);
        float acc0 = 0.f, acc1 = 0.f, acc2 = 0.f, acc3 = 0.f;

        // stage chunk 0 (16 KB)
        {
            const float4* src = (const float4*)hb;
            const float4 v0 = src[tid], v1 = src[tid + 256],
                         v2 = src[tid + 512], v3 = src[tid + 768];
            float4* dst = (float4*)h_s[0];
            dst[tid] = v0; dst[tid + 256] = v1; dst[tid + 512] = v2; dst[tid + 768] = v3;
        }
        __syncthreads();

        #pragma unroll 1
        for (int c = 0; c < 8; ++c) {
            float4 p0, p1, p2, p3;
            if (c < 7) {   // prefetch chunk c+1 (overlaps compute below)
                const float4* src = (const float4*)(hb + (c + 1) * 4096);
                p0 = src[tid]; p1 = src[tid + 256]; p2 = src[tid + 512]; p3 = src[tid + 768];
            }
            const float* w0p = &wh_s[wv][0][c * 64];
            const float* w1p = &wh_s[wv][1][c * 64];
            const float* w2p = &wh_s[wv][2][c * 64];
            const float* w3p = &wh_s[wv][3][c * 64];
            const float* hc  = h_s[c & 1];
            #pragma unroll
            for (int kg = 0; kg < 64; kg += 4) {
                const float4 w0 = *(const float4*)(w0p + kg);   // b128 broadcast
                const float4 w1 = *(const float4*)(w1p + kg);
                const float4 w2 = *(const float4*)(w2p + kg);
                const float4 w3 = *(const float4*)(w3p + kg);
                const float hv0 = hc[(kg + 0) * 64 + b];        // b32 conflict-free
                const float hv1 = hc[(kg + 1) * 64 + b];
                const float hv2 = hc[(kg + 2) * 64 + b];
                const float hv3 = hc[(kg + 3) * 64 + b];
                acc0 += hv0 * w0.x + hv1 * w0.y + hv2 * w0.z + hv3 * w0.w;
                acc1 += hv0 * w1.x + hv1 * w1.y + hv2 * w1.z + hv3 * w1.w;
                acc2 += hv0 * w2.x + hv1 * w2.y + hv2 * w2.z + hv3 * w2.w;
                acc3 += hv0 * w3.x + hv1 * w3.y + hv2 * w3.z + hv3 * w3.w;
            }
            if (c < 7) {
                float4* dst = (float4*)h_s[(c + 1) & 1];
                dst[tid] = p0; dst[tid + 256] = p1; dst[tid + 512] = p2; dst[tid + 768] = p3;
            }
            __syncthreads();
        }

        // gates (c state in VGPR across all 512 steps)
        const float ig = sigmoidf_(acc0 + bf2f(x0));
        const float fg = sigmoidf_(acc1 + bf2f(x1));
        const float og = sigmoidf_(acc2 + bf2f(x2));
        const float gg = tanhf_  (acc3 + bf2f(x3));
        creg = fg * creg + ig * gg;
        const float hnew = og * tanhf_(creg);

        // publish h(t+1): write-through store; order via barrier (vmcnt drain)
        // + release RMW by tid 0.
        float* hbn = h_buf + (size_t)((t + 1) & 1) * (DK * 64);
        __hip_atomic_store(&hbn[u * 64 + b], hnew, __ATOMIC_RELAXED,
                           __HIP_MEMORY_SCOPE_AGENT);
        h_s[0][wv * 64 + b] = hnew;     // out-transpose staging (safe: chunk loop done)
        __syncthreads();
        if (wv == 0) {
            float4 o4;
            o4.x = h_s[0][b]; o4.y = h_s[0][64 + b];
            o4.z = h_s[0][128 + b]; o4.w = h_s[0][192 + b];
            *(float4*)(out + ((size_t)b * TSTEPS + t) * DK + 4 * g) = o4;
        }
        if (tid == 0)
            __hip_atomic_fetch_add(&cnt[grp * 16], 1u, __ATOMIC_RELEASE,
                                   __HIP_MEMORY_SCOPE_AGENT);
    }
}

// ---------------------------------------------------------------------------
extern "C" void kernel_launch(void* const* d_in, const int* in_sizes, int n_in,
                              void* d_out, int out_size, void* d_ws, size_t ws_size,
                              hipStream_t stream) {
    const float* x    = (const float*)d_in[0];
    const float* h0   = (const float*)d_in[1];
    const float* Wx   = (const float*)d_in[2];
    const float* Wh   = (const float*)d_in[3];
    const float* bias = (const float*)d_in[4];
    float* out = (float*)d_out;

    u16* xw = (u16*)d_ws;
    const size_t XW_BYTES = (size_t)TSTEPS * NC * 64 * sizeof(u16);   // 134217728
    float* h_buf = (float*)((char*)d_ws + XW_BYTES);                  // 2*512*64 f32
    u32*   cnt   = (u32*)((char*)d_ws + XW_BYTES + 262144);           // 8 ctrs, 64B apart
    const size_t need = XW_BYTES + 262144 + 512;

    if (ws_size >= need) {
        dim3 g1(TSTEPS, 32);
        gemm_xwt<<<g1, 256, 0, stream>>>(x, Wx, bias, xw);
        init_cnt<<<1, 64, 0, stream>>>(cnt);
        lstm_rec3<<<NWG, WGT, 0, stream>>>(xw, Wh, h0, out, h_buf, cnt);
    } else {
        dim3 g1(512, 32);
        gemm_xw<<<g1, 256, 0, stream>>>(x, Wx, bias, xw);
        lstm_rec_old<<<64, 512, 0, stream>>>(xw, Wh, h0, out);
    }
}

// Round 4
// 5448.454 us; speedup vs baseline: 2.2996x; 2.2996x over previous
//
#include <hip/hip_runtime.h>

#define TSTEPS 512
#define DK 512       // D == H == 512
#define NC 2048      // 4H

typedef unsigned int u32;
typedef unsigned short u16;
typedef __attribute__((ext_vector_type(8))) short bf16x8;
typedef __attribute__((ext_vector_type(4))) float f32x4;

static __device__ __forceinline__ float bf2f(u16 u) {
    return __uint_as_float(((u32)u) << 16);
}
static __device__ __forceinline__ u16 f2bf(float f) {
    u32 u = __float_as_uint(f);
    u += 0x7fffu + ((u >> 16) & 1u);
    return (u16)(u >> 16);
}
static __device__ __forceinline__ float sigmoidf_(float x) { return 1.0f / (1.0f + __expf(-x)); }
static __device__ __forceinline__ float tanhf_(float x)    { return 1.0f - 2.0f / (__expf(2.0f * x) + 1.0f); }

// MFMA A/B fragment address (u16 units) for element (k, n) of a 16xK (or Kx16)
// operand: K0=k>>5 block of 1024 B; lane L = n | (((k>>3)&3)<<4); sub j = k&7.
static __device__ __forceinline__ int fragaddr(int k, int n) {
    return ((k >> 5) << 9) + ((n | (((k >> 3) & 3) << 4)) << 3) + (k & 7);
}

static __device__ __forceinline__ void gl_lds16(const void* g, void* l) {
    __builtin_amdgcn_global_load_lds(
        (const __attribute__((address_space(1))) unsigned int*)g,
        (__attribute__((address_space(3))) unsigned int*)l, 16, 0, 0);
}

// ---------------------------------------------------------------------------
// K1: transposed-output GEMM (unchanged, verified round 3).
// xwt[(t*NC + c)*64 + b] = bf16( sum_k x[b][t][k]*Wx[k][c] + bias[c] )
// ---------------------------------------------------------------------------
__global__ __launch_bounds__(256)
void gemm_xwt(const float* __restrict__ x, const float* __restrict__ Wx,
              const float* __restrict__ bias, u16* __restrict__ xwt) {
    __shared__ float As[16][64];
    __shared__ float Bs[16][68];
    const int tid = threadIdx.x;
    const int t   = blockIdx.x;
    const int c0  = blockIdx.y * 64;
    const int lk  = tid >> 4;
    const int lc  = (tid & 15) << 2;
    const int lb  = tid >> 2;
    const int lkx = (tid & 3) << 2;
    const int tc  = tid & 15;
    const int tb  = tid >> 4;
    float acc[4][4] = {};
    for (int k0 = 0; k0 < DK; k0 += 16) {
        const float4 av = *(const float4*)(Wx + (size_t)(k0 + lk) * NC + c0 + lc);
        const float4 bv = *(const float4*)(x + ((size_t)lb * TSTEPS + t) * DK + k0 + lkx);
        __syncthreads();
        *(float4*)&As[lk][lc] = av;
        Bs[lkx + 0][lb] = bv.x;
        Bs[lkx + 1][lb] = bv.y;
        Bs[lkx + 2][lb] = bv.z;
        Bs[lkx + 3][lb] = bv.w;
        __syncthreads();
        #pragma unroll
        for (int k = 0; k < 16; ++k) {
            float a4[4], b4[4];
            *(float4*)a4 = *(const float4*)&As[k][tc << 2];
            *(float4*)b4 = *(const float4*)&Bs[k][tb << 2];
            #pragma unroll
            for (int i = 0; i < 4; ++i)
                #pragma unroll
                for (int j = 0; j < 4; ++j)
                    acc[i][j] += a4[i] * b4[j];
        }
    }
    const float4 bias4 = *(const float4*)(bias + c0 + (tc << 2));
    const float bi[4] = {bias4.x, bias4.y, bias4.z, bias4.w};
    #pragma unroll
    for (int i = 0; i < 4; ++i) {
        const size_t row = (size_t)t * NC + c0 + (tc << 2) + i;
        ushort4 s;
        s.x = f2bf(acc[i][0] + bi[i]);
        s.y = f2bf(acc[i][1] + bi[i]);
        s.z = f2bf(acc[i][2] + bi[i]);
        s.w = f2bf(acc[i][3] + bi[i]);
        *(ushort4*)(xwt + row * 64 + (tb << 2)) = s;
    }
}

// ---------------------------------------------------------------------------
// Fallbacks (ws too small): round-1 kernels, [b][t][c] layout.
// ---------------------------------------------------------------------------
__global__ __launch_bounds__(256)
void gemm_xw(const float* __restrict__ x, const float* __restrict__ Wx,
             const float* __restrict__ bias, u16* __restrict__ xw_out) {
    __shared__ float As[16][68];
    __shared__ float Bs[16][64];
    const int tid  = threadIdx.x;
    const int tx   = tid & 15;
    const int ty   = tid >> 4;
    const int row0 = blockIdx.x * 64;
    const int col0 = blockIdx.y * 64;
    const int ar = tid >> 2;
    const int ak = (tid & 3) << 2;
    const int bk = tid >> 4;
    const int bc = (tid & 15) << 2;
    float acc[4][4] = {};
    for (int k0 = 0; k0 < DK; k0 += 16) {
        const float4 av = *(const float4*)(x  + (size_t)(row0 + ar) * DK + k0 + ak);
        const float4 bv = *(const float4*)(Wx + (size_t)(k0 + bk) * NC + col0 + bc);
        __syncthreads();
        As[ak + 0][ar] = av.x; As[ak + 1][ar] = av.y;
        As[ak + 2][ar] = av.z; As[ak + 3][ar] = av.w;
        *(float4*)&Bs[bk][bc] = bv;
        __syncthreads();
        #pragma unroll
        for (int k = 0; k < 16; ++k) {
            float a4[4], b4[4];
            *(float4*)a4 = *(const float4*)&As[k][ty << 2];
            *(float4*)b4 = *(const float4*)&Bs[k][tx << 2];
            #pragma unroll
            for (int i = 0; i < 4; ++i)
                #pragma unroll
                for (int j = 0; j < 4; ++j)
                    acc[i][j] += a4[i] * b4[j];
        }
    }
    #pragma unroll
    for (int i = 0; i < 4; ++i) {
        const size_t row = (size_t)row0 + (ty << 2) + i;
        const int    col = col0 + (tx << 2);
        ushort4 s;
        s.x = f2bf(acc[i][0] + bias[col + 0]);
        s.y = f2bf(acc[i][1] + bias[col + 1]);
        s.z = f2bf(acc[i][2] + bias[col + 2]);
        s.w = f2bf(acc[i][3] + bias[col + 3]);
        *(ushort4*)(xw_out + row * NC + col) = s;
    }
}

__global__ __launch_bounds__(512)
void lstm_rec_old(const u16* __restrict__ xw, const float* __restrict__ Wh,
                  const float* __restrict__ h0, float* __restrict__ out) {
    __shared__ float h_s[DK];
    __shared__ float c_s[DK];
    __shared__ float a_s[NC];
    const int b   = blockIdx.x;
    const int tid = threadIdx.x;
    const int q   = tid << 2;
    h_s[tid] = h0[(size_t)b * DK + tid];
    c_s[tid] = 0.0f;
    __syncthreads();
    for (int t = 0; t < TSTEPS; ++t) {
        const size_t rowoff = ((size_t)b * TSTEPS + t) * NC;
        const ushort4 xv = *(const ushort4*)(xw + rowoff + q);
        float4 acc;
        acc.x = bf2f(xv.x); acc.y = bf2f(xv.y); acc.z = bf2f(xv.z); acc.w = bf2f(xv.w);
        const float* wp = Wh + q;
        #pragma unroll 4
        for (int k = 0; k < DK; k += 4) {
            const float4 hk = *(const float4*)&h_s[k];
            const float4 w0 = *(const float4*)(wp + (size_t)(k + 0) * NC);
            const float4 w1 = *(const float4*)(wp + (size_t)(k + 1) * NC);
            const float4 w2 = *(const float4*)(wp + (size_t)(k + 2) * NC);
            const float4 w3 = *(const float4*)(wp + (size_t)(k + 3) * NC);
            acc.x += hk.x * w0.x + hk.y * w1.x + hk.z * w2.x + hk.w * w3.x;
            acc.y += hk.x * w0.y + hk.y * w1.y + hk.z * w2.y + hk.w * w3.y;
            acc.z += hk.x * w0.z + hk.y * w1.z + hk.z * w2.z + hk.w * w3.z;
            acc.w += hk.x * w0.w + hk.y * w1.w + hk.z * w2.w + hk.w * w3.w;
        }
        *(float4*)&a_s[q] = acc;
        __syncthreads();
        const float ig = sigmoidf_(a_s[tid]);
        const float fg = sigmoidf_(a_s[DK + tid]);
        const float og = sigmoidf_(a_s[2 * DK + tid]);
        const float gg = tanhf_(a_s[3 * DK + tid]);
        const float c  = fg * c_s[tid] + ig * gg;
        const float h  = og * tanhf_(c);
        c_s[tid] = c;
        h_s[tid] = h;
        out[((size_t)b * TSTEPS + t) * DK + tid] = h;
        __syncthreads();
    }
}

// ---------------------------------------------------------------------------
__global__ void init_cnt(u32* cnt) {
    const int i = threadIdx.x;
    if (i < 8) cnt[i * 16] = 0u;
}

// ---------------------------------------------------------------------------
// K2 (v4): MFMA recurrent kernel.
// 128 WGs x 256 thr = 4 batch-groups (i, 16 b) x 32 unit-groups (j, 16 u).
// Batch-groups are independent: counter[i] incremented once per WG per step
// by the 32 WGs of group i; consumers poll only counter[i].
// Per WG: a[16b x 64cols] = h[16b x 512] @ Wh[512 x 64cols], via
// mfma_f32_16x16x32_bf16; wave wv computes gate wv (16 cols = 16 units).
// Wh fragments preloaded to VGPRs (16 x bf16x8). h exchanged through global
// hG in A-fragment order, bf16 hi+lo planes; staging = straight 32 KB copy
// via global_load_lds; A-frags = ds_read_b128.
// ---------------------------------------------------------------------------
__global__ __launch_bounds__(256, 1)
void lstm_rec4(const u16* __restrict__ xwt, const float* __restrict__ Wh,
               const float* __restrict__ h0, float* __restrict__ out,
               u16* __restrict__ hG, u32* __restrict__ cnt) {
    __shared__ __align__(16) u16 hF[2][8192];   // [hi/lo][frag order]  32 KB
    __shared__ float Cx[4 * 256];               // [gate][unit][b']      4 KB
    __shared__ float hT[256];                   // [unit][b']            1 KB

    const int tid  = threadIdx.x;
    const int lane = tid & 63;
    const int wv   = __builtin_amdgcn_readfirstlane(tid >> 6);  // wave = gate
    const int g    = blockIdx.x;
    const int j    = g & 31;       // unit-group
    const int i    = g >> 5;       // batch-group
    const int du   = tid >> 4;     // gate-phase: local unit 0..15
    const int bp   = tid & 15;     // gate-phase: local batch 0..15
    const int u    = 16 * j + du;  // global unit
    const int b    = 16 * i + bp;  // global batch

    // ---- B-fragment preload to VGPRs: Bf[K0][jj] = Wh[k][wv*512+16j+(lane&15)]
    bf16x8 Bf[16];
    {
        const int coln = 16 * j + (lane & 15);
        #pragma unroll
        for (int K0 = 0; K0 < 16; ++K0) {
            bf16x8 bv;
            #pragma unroll
            for (int jj = 0; jj < 8; ++jj) {
                const int k = K0 * 32 + ((lane >> 4) << 3) + jj;
                bv[jj] = (short)f2bf(Wh[(size_t)k * NC + wv * 512 + coln]);
            }
            Bf[K0] = bv;
        }
    }

    // ---- h0 publish into hG buf 0, plane i (frag order, hi+lo)
    {
        const float h0v = h0[(size_t)b * DK + u];
        const u16 hi = f2bf(h0v);
        const u16 lo = f2bf(h0v - bf2f(hi));
        u16* dst = hG + ((size_t)0 * 4 + i) * 2 * 8192;
        const int fa = fragaddr(u, bp);
        __hip_atomic_store(&dst[fa], hi, __ATOMIC_RELAXED, __HIP_MEMORY_SCOPE_AGENT);
        __hip_atomic_store(&dst[8192 + fa], lo, __ATOMIC_RELAXED, __HIP_MEMORY_SCOPE_AGENT);
    }
    float creg = 0.0f;
    __syncthreads();
    if (tid == 0)
        __hip_atomic_fetch_add(&cnt[i * 16], 1u, __ATOMIC_RELEASE, __HIP_MEMORY_SCOPE_AGENT);

    for (int t = 0; t < TSTEPS; ++t) {
        // xw prefetch (coalesced 32B runs), in flight during spin
        const u16* xp = xwt + (size_t)t * (NC * 64);
        const u16 x0 = xp[(0 * 512 + u) * 64 + b];
        const u16 x1 = xp[(1 * 512 + u) * 64 + b];
        const u16 x2 = xp[(2 * 512 + u) * 64 + b];
        const u16 x3 = xp[(3 * 512 + u) * 64 + b];

        // ---- wait for group-i h(t)
        const u32 target = 32u * (u32)(t + 1);
        if (tid == 0) {
            while (__hip_atomic_load(&cnt[i * 16], __ATOMIC_RELAXED,
                                     __HIP_MEMORY_SCOPE_AGENT) < target)
                __builtin_amdgcn_s_sleep(1);
        }
        __syncthreads();
        __builtin_amdgcn_fence(__ATOMIC_ACQUIRE, "agent");

        // ---- stage 32 KB (hi+lo planes, contiguous) via global_load_lds
        {
            const char* src = (const char*)(hG + ((size_t)(t & 1) * 4 + i) * 2 * 8192);
            char* dstl = (char*)&hF[0][0];
            #pragma unroll
            for (int m = 0; m < 8; ++m) {
                const int off = wv * 8192 + m * 1024;
                gl_lds16(src + off + lane * 16, dstl + off);
            }
        }
        __syncthreads();

        // ---- MFMA: acc[16b x 16cols] over K=512, hi+lo accumulated separately
        f32x4 acc_h = {0.f, 0.f, 0.f, 0.f};
        f32x4 acc_l = {0.f, 0.f, 0.f, 0.f};
        #pragma unroll
        for (int K0 = 0; K0 < 16; ++K0) {
            const bf16x8 ah = *(const bf16x8*)&hF[0][K0 * 512 + lane * 8];
            const bf16x8 al = *(const bf16x8*)&hF[1][K0 * 512 + lane * 8];
            acc_h = __builtin_amdgcn_mfma_f32_16x16x32_bf16(ah, Bf[K0], acc_h, 0, 0, 0);
            acc_l = __builtin_amdgcn_mfma_f32_16x16x32_bf16(al, Bf[K0], acc_l, 0, 0, 0);
        }
        const f32x4 accv = acc_h + acc_l;

        // C layout: col=lane&15 (unit), row=(lane>>4)*4+r (b'). -> Cx[gate][unit][b']
        #pragma unroll
        for (int r = 0; r < 4; ++r)
            Cx[wv * 256 + (lane & 15) * 16 + ((lane >> 4) << 2) + r] = accv[r];
        __syncthreads();

        // ---- gate phase: thread (du, bp)
        const float ai = Cx[0 * 256 + du * 16 + bp] + bf2f(x0);
        const float af = Cx[1 * 256 + du * 16 + bp] + bf2f(x1);
        const float ao = Cx[2 * 256 + du * 16 + bp] + bf2f(x2);
        const float ag = Cx[3 * 256 + du * 16 + bp] + bf2f(x3);
        const float ig = sigmoidf_(ai);
        const float fg = sigmoidf_(af);
        const float og = sigmoidf_(ao);
        const float gg = tanhf_(ag);
        creg = fg * creg + ig * gg;
        const float hnew = og * tanhf_(creg);

        // publish h(t+1) (frag order, hi+lo, write-through)
        {
            const u16 hi = f2bf(hnew);
            const u16 lo = f2bf(hnew - bf2f(hi));
            u16* dst = hG + ((size_t)((t + 1) & 1) * 4 + i) * 2 * 8192;
            const int fa = fragaddr(u, bp);
            __hip_atomic_store(&dst[fa], hi, __ATOMIC_RELAXED, __HIP_MEMORY_SCOPE_AGENT);
            __hip_atomic_store(&dst[8192 + fa], lo, __ATOMIC_RELAXED, __HIP_MEMORY_SCOPE_AGENT);
        }
        hT[tid] = hnew;   // hT[du*16+bp]
        __syncthreads();  // publish stores drained (vmcnt 0) + hT visible

        if (wv == 0) {    // out[b][t][16j+qd*4 .. +4]
            const int bq = lane >> 2;
            const int qd = lane & 3;
            float4 o4;
            o4.x = hT[(qd * 4 + 0) * 16 + bq];
            o4.y = hT[(qd * 4 + 1) * 16 + bq];
            o4.z = hT[(qd * 4 + 2) * 16 + bq];
            o4.w = hT[(qd * 4 + 3) * 16 + bq];
            *(float4*)(out + ((size_t)(16 * i + bq) * TSTEPS + t) * DK + 16 * j + qd * 4) = o4;
        }
        if (tid == 0)
            __hip_atomic_fetch_add(&cnt[i * 16], 1u, __ATOMIC_RELEASE,
                                   __HIP_MEMORY_SCOPE_AGENT);
    }
}

// ---------------------------------------------------------------------------
extern "C" void kernel_launch(void* const* d_in, const int* in_sizes, int n_in,
                              void* d_out, int out_size, void* d_ws, size_t ws_size,
                              hipStream_t stream) {
    const float* x    = (const float*)d_in[0];
    const float* h0   = (const float*)d_in[1];
    const float* Wx   = (const float*)d_in[2];
    const float* Wh   = (const float*)d_in[3];
    const float* bias = (const float*)d_in[4];
    float* out = (float*)d_out;

    u16* xw = (u16*)d_ws;
    const size_t XW_BYTES = (size_t)TSTEPS * NC * 64 * sizeof(u16);   // 134217728
    u16* hG    = (u16*)((char*)d_ws + XW_BYTES);                      // 256 KB (2 bufs x 4 planes x hi/lo x 16 KB)
    u32* cnt   = (u32*)((char*)d_ws + XW_BYTES + 262144);             // 4 ctrs, 64B apart
    const size_t need = XW_BYTES + 262144 + 512;

    if (ws_size >= need) {
        dim3 g1(TSTEPS, 32);
        gemm_xwt<<<g1, 256, 0, stream>>>(x, Wx, bias, xw);
        init_cnt<<<1, 64, 0, stream>>>(cnt);
        lstm_rec4<<<128, 256, 0, stream>>>(xw, Wh, h0, out, hG, cnt);
    } else {
        dim3 g1(512, 32);
        gemm_xw<<<g1, 256, 0, stream>>>(x, Wx, bias, xw);
        lstm_rec_old<<<64, 512, 0, stream>>>(xw, Wh, h0, out);
    }
}

// Round 5
// 4995.158 us; speedup vs baseline: 2.5083x; 1.0907x over previous
//
#include <hip/hip_runtime.h>

#define TSTEPS 512
#define DK 512       // D == H == 512
#define NC 2048      // 4H

typedef unsigned int u32;
typedef unsigned short u16;
typedef __attribute__((ext_vector_type(8))) short bf16x8;
typedef __attribute__((ext_vector_type(4))) float f32x4;

static __device__ __forceinline__ float bf2f(u16 u) {
    return __uint_as_float(((u32)u) << 16);
}
static __device__ __forceinline__ u16 f2bf(float f) {
    u32 u = __float_as_uint(f);
    u += 0x7fffu + ((u >> 16) & 1u);
    return (u16)(u >> 16);
}
static __device__ __forceinline__ float sigmoidf_(float x) { return 1.0f / (1.0f + __expf(-x)); }
static __device__ __forceinline__ float tanhf_(float x)    { return 1.0f - 2.0f / (__expf(2.0f * x) + 1.0f); }

// MFMA A/B fragment address (u16 units) for element (k, n) of a 16xK (or Kx16)
// operand: K0=k>>5 block of 1024 B; lane L = n | (((k>>3)&3)<<4); sub j = k&7.
static __device__ __forceinline__ int fragaddr(int k, int n) {
    return ((k >> 5) << 9) + ((n | (((k >> 3) & 3) << 4)) << 3) + (k & 7);
}

static __device__ __forceinline__ void gl_lds16(const void* g, void* l) {
    __builtin_amdgcn_global_load_lds(
        (const __attribute__((address_space(1))) unsigned int*)g,
        (__attribute__((address_space(3))) unsigned int*)l, 16, 0, 0);
}

// ---------------------------------------------------------------------------
// K1: transposed-output GEMM (unchanged, verified rounds 3-4).
// xwt[(t*NC + c)*64 + b] = bf16( sum_k x[b][t][k]*Wx[k][c] + bias[c] )
// ---------------------------------------------------------------------------
__global__ __launch_bounds__(256)
void gemm_xwt(const float* __restrict__ x, const float* __restrict__ Wx,
              const float* __restrict__ bias, u16* __restrict__ xwt) {
    __shared__ float As[16][64];
    __shared__ float Bs[16][68];
    const int tid = threadIdx.x;
    const int t   = blockIdx.x;
    const int c0  = blockIdx.y * 64;
    const int lk  = tid >> 4;
    const int lc  = (tid & 15) << 2;
    const int lb  = tid >> 2;
    const int lkx = (tid & 3) << 2;
    const int tc  = tid & 15;
    const int tb  = tid >> 4;
    float acc[4][4] = {};
    for (int k0 = 0; k0 < DK; k0 += 16) {
        const float4 av = *(const float4*)(Wx + (size_t)(k0 + lk) * NC + c0 + lc);
        const float4 bv = *(const float4*)(x + ((size_t)lb * TSTEPS + t) * DK + k0 + lkx);
        __syncthreads();
        *(float4*)&As[lk][lc] = av;
        Bs[lkx + 0][lb] = bv.x;
        Bs[lkx + 1][lb] = bv.y;
        Bs[lkx + 2][lb] = bv.z;
        Bs[lkx + 3][lb] = bv.w;
        __syncthreads();
        #pragma unroll
        for (int k = 0; k < 16; ++k) {
            float a4[4], b4[4];
            *(float4*)a4 = *(const float4*)&As[k][tc << 2];
            *(float4*)b4 = *(const float4*)&Bs[k][tb << 2];
            #pragma unroll
            for (int i = 0; i < 4; ++i)
                #pragma unroll
                for (int j = 0; j < 4; ++j)
                    acc[i][j] += a4[i] * b4[j];
        }
    }
    const float4 bias4 = *(const float4*)(bias + c0 + (tc << 2));
    const float bi[4] = {bias4.x, bias4.y, bias4.z, bias4.w};
    #pragma unroll
    for (int i = 0; i < 4; ++i) {
        const size_t row = (size_t)t * NC + c0 + (tc << 2) + i;
        ushort4 s;
        s.x = f2bf(acc[i][0] + bi[i]);
        s.y = f2bf(acc[i][1] + bi[i]);
        s.z = f2bf(acc[i][2] + bi[i]);
        s.w = f2bf(acc[i][3] + bi[i]);
        *(ushort4*)(xwt + row * 64 + (tb << 2)) = s;
    }
}

// ---------------------------------------------------------------------------
// Fallbacks (ws too small): round-1 kernels, [b][t][c] layout.
// ---------------------------------------------------------------------------
__global__ __launch_bounds__(256)
void gemm_xw(const float* __restrict__ x, const float* __restrict__ Wx,
             const float* __restrict__ bias, u16* __restrict__ xw_out) {
    __shared__ float As[16][68];
    __shared__ float Bs[16][64];
    const int tid  = threadIdx.x;
    const int tx   = tid & 15;
    const int ty   = tid >> 4;
    const int row0 = blockIdx.x * 64;
    const int col0 = blockIdx.y * 64;
    const int ar = tid >> 2;
    const int ak = (tid & 3) << 2;
    const int bk = tid >> 4;
    const int bc = (tid & 15) << 2;
    float acc[4][4] = {};
    for (int k0 = 0; k0 < DK; k0 += 16) {
        const float4 av = *(const float4*)(x  + (size_t)(row0 + ar) * DK + k0 + ak);
        const float4 bv = *(const float4*)(Wx + (size_t)(k0 + bk) * NC + col0 + bc);
        __syncthreads();
        As[ak + 0][ar] = av.x; As[ak + 1][ar] = av.y;
        As[ak + 2][ar] = av.z; As[ak + 3][ar] = av.w;
        *(float4*)&Bs[bk][bc] = bv;
        __syncthreads();
        #pragma unroll
        for (int k = 0; k < 16; ++k) {
            float a4[4], b4[4];
            *(float4*)a4 = *(const float4*)&As[k][ty << 2];
            *(float4*)b4 = *(const float4*)&Bs[k][tx << 2];
            #pragma unroll
            for (int i = 0; i < 4; ++i)
                #pragma unroll
                for (int j = 0; j < 4; ++j)
                    acc[i][j] += a4[i] * b4[j];
        }
    }
    #pragma unroll
    for (int i = 0; i < 4; ++i) {
        const size_t row = (size_t)row0 + (ty << 2) + i;
        const int    col = col0 + (tx << 2);
        ushort4 s;
        s.x = f2bf(acc[i][0] + bias[col + 0]);
        s.y = f2bf(acc[i][1] + bias[col + 1]);
        s.z = f2bf(acc[i][2] + bias[col + 2]);
        s.w = f2bf(acc[i][3] + bias[col + 3]);
        *(ushort4*)(xw_out + row * NC + col) = s;
    }
}

__global__ __launch_bounds__(512)
void lstm_rec_old(const u16* __restrict__ xw, const float* __restrict__ Wh,
                  const float* __restrict__ h0, float* __restrict__ out) {
    __shared__ float h_s[DK];
    __shared__ float c_s[DK];
    __shared__ float a_s[NC];
    const int b   = blockIdx.x;
    const int tid = threadIdx.x;
    const int q   = tid << 2;
    h_s[tid] = h0[(size_t)b * DK + tid];
    c_s[tid] = 0.0f;
    __syncthreads();
    for (int t = 0; t < TSTEPS; ++t) {
        const size_t rowoff = ((size_t)b * TSTEPS + t) * NC;
        const ushort4 xv = *(const ushort4*)(xw + rowoff + q);
        float4 acc;
        acc.x = bf2f(xv.x); acc.y = bf2f(xv.y); acc.z = bf2f(xv.z); acc.w = bf2f(xv.w);
        const float* wp = Wh + q;
        #pragma unroll 4
        for (int k = 0; k < DK; k += 4) {
            const float4 hk = *(const float4*)&h_s[k];
            const float4 w0 = *(const float4*)(wp + (size_t)(k + 0) * NC);
            const float4 w1 = *(const float4*)(wp + (size_t)(k + 1) * NC);
            const float4 w2 = *(const float4*)(wp + (size_t)(k + 2) * NC);
            const float4 w3 = *(const float4*)(wp + (size_t)(k + 3) * NC);
            acc.x += hk.x * w0.x + hk.y * w1.x + hk.z * w2.x + hk.w * w3.x;
            acc.y += hk.x * w0.y + hk.y * w1.y + hk.z * w2.y + hk.w * w3.y;
            acc.z += hk.x * w0.z + hk.y * w1.z + hk.z * w2.z + hk.w * w3.z;
            acc.w += hk.x * w0.w + hk.y * w1.w + hk.z * w2.w + hk.w * w3.w;
        }
        *(float4*)&a_s[q] = acc;
        __syncthreads();
        const float ig = sigmoidf_(a_s[tid]);
        const float fg = sigmoidf_(a_s[DK + tid]);
        const float og = sigmoidf_(a_s[2 * DK + tid]);
        const float gg = tanhf_(a_s[3 * DK + tid]);
        const float c  = fg * c_s[tid] + ig * gg;
        const float h  = og * tanhf_(c);
        c_s[tid] = c;
        h_s[tid] = h;
        out[((size_t)b * TSTEPS + t) * DK + tid] = h;
        __syncthreads();
    }
}

// ---------------------------------------------------------------------------
__global__ void init_flg(u32* flg) {
    const int i = threadIdx.x;
    if (i < 128) flg[i] = 0u;
}

// ---------------------------------------------------------------------------
// K2 (v5): per-WG flag handshake (no RMW serialization).
// 128 WGs x 256 thr = 4 batch-groups (i, 16 b) x 32 unit-groups (j, 16 u).
// flg[i][w], w=0..31: one 128-B line per group. Producer: h stores ->
// __syncthreads (drains vmcnt in every wave) -> tid0 release-stores
// flg[i][j] = t+2 (own word; stores to distinct words pipeline at L3).
// Consumer: all lanes poll flg[i][lane&31] (one load, one line),
// __all(v >= t+1), then one acquire fence. Datapath identical to v4:
// mfma_f32_16x16x32_bf16, Wh B-frags in VGPRs, h hi+lo bf16 planes in
// A-fragment order, global_load_lds staging. Cx padded to stride 17
// (kills the 8-way bank conflict seen in round 4).
// ---------------------------------------------------------------------------
__global__ __launch_bounds__(256, 1)
void lstm_rec5(const u16* __restrict__ xwt, const float* __restrict__ Wh,
               const float* __restrict__ h0, float* __restrict__ out,
               u16* __restrict__ hG, u32* __restrict__ flg) {
    __shared__ __align__(16) u16 hF[2][8192];   // [hi/lo][frag order]  32 KB
    __shared__ float Cx[4][16][17];             // [gate][unit][b'] pad  4.25 KB
    __shared__ float hT[256];                   // [unit][b']            1 KB

    const int tid  = threadIdx.x;
    const int lane = tid & 63;
    const int wv   = __builtin_amdgcn_readfirstlane(tid >> 6);  // wave = gate
    const int g    = blockIdx.x;
    const int j    = g & 31;       // unit-group
    const int i    = g >> 5;       // batch-group
    const int du   = tid >> 4;     // gate-phase: local unit 0..15
    const int bp   = tid & 15;     // gate-phase: local batch 0..15
    const int u    = 16 * j + du;  // global unit
    const int b    = 16 * i + bp;  // global batch

    // ---- B-fragment preload to VGPRs: Bf[K0][jj] = Wh[k][wv*512+16j+(lane&15)]
    bf16x8 Bf[16];
    {
        const int coln = 16 * j + (lane & 15);
        #pragma unroll
        for (int K0 = 0; K0 < 16; ++K0) {
            bf16x8 bv;
            #pragma unroll
            for (int jj = 0; jj < 8; ++jj) {
                const int k = K0 * 32 + ((lane >> 4) << 3) + jj;
                bv[jj] = (short)f2bf(Wh[(size_t)k * NC + wv * 512 + coln]);
            }
            Bf[K0] = bv;
        }
    }

    // ---- h0 publish into hG buf 0, plane i (frag order, hi+lo)
    {
        const float h0v = h0[(size_t)b * DK + u];
        const u16 hi = f2bf(h0v);
        const u16 lo = f2bf(h0v - bf2f(hi));
        u16* dst = hG + ((size_t)0 * 4 + i) * 2 * 8192;
        const int fa = fragaddr(u, bp);
        __hip_atomic_store(&dst[fa], hi, __ATOMIC_RELAXED, __HIP_MEMORY_SCOPE_AGENT);
        __hip_atomic_store(&dst[8192 + fa], lo, __ATOMIC_RELAXED, __HIP_MEMORY_SCOPE_AGENT);
    }
    float creg = 0.0f;
    __syncthreads();   // drains all waves' vmcnt before the flag release
    if (tid == 0)
        __hip_atomic_store(&flg[(i << 5) + j], 1u, __ATOMIC_RELEASE,
                           __HIP_MEMORY_SCOPE_AGENT);

    for (int t = 0; t < TSTEPS; ++t) {
        // xw prefetch (coalesced 32B runs), in flight during spin
        const u16* xp = xwt + (size_t)t * (NC * 64);
        const u16 x0 = xp[(0 * 512 + u) * 64 + b];
        const u16 x1 = xp[(1 * 512 + u) * 64 + b];
        const u16 x2 = xp[(2 * 512 + u) * 64 + b];
        const u16 x3 = xp[(3 * 512 + u) * 64 + b];

        // ---- wait for group-i h(t): all lanes poll one cacheline of flags
        {
            const u32 target = (u32)(t + 1);
            const u32* fp = &flg[(i << 5) + (lane & 31)];
            while (true) {
                const u32 v = __hip_atomic_load(fp, __ATOMIC_RELAXED,
                                                __HIP_MEMORY_SCOPE_AGENT);
                if (__all((int)(v >= target))) break;
                __builtin_amdgcn_s_sleep(1);
            }
        }
        __builtin_amdgcn_fence(__ATOMIC_ACQUIRE, "agent");

        // ---- stage 32 KB (hi+lo planes, contiguous) via global_load_lds
        {
            const char* src = (const char*)(hG + ((size_t)(t & 1) * 4 + i) * 2 * 8192);
            char* dstl = (char*)&hF[0][0];
            #pragma unroll
            for (int m = 0; m < 8; ++m) {
                const int off = wv * 8192 + m * 1024;
                gl_lds16(src + off + lane * 16, dstl + off);
            }
        }
        __syncthreads();

        // ---- MFMA: acc[16b x 16cols] over K=512, hi+lo accumulated separately
        f32x4 acc_h = {0.f, 0.f, 0.f, 0.f};
        f32x4 acc_l = {0.f, 0.f, 0.f, 0.f};
        #pragma unroll
        for (int K0 = 0; K0 < 16; ++K0) {
            const bf16x8 ah = *(const bf16x8*)&hF[0][K0 * 512 + lane * 8];
            const bf16x8 al = *(const bf16x8*)&hF[1][K0 * 512 + lane * 8];
            acc_h = __builtin_amdgcn_mfma_f32_16x16x32_bf16(ah, Bf[K0], acc_h, 0, 0, 0);
            acc_l = __builtin_amdgcn_mfma_f32_16x16x32_bf16(al, Bf[K0], acc_l, 0, 0, 0);
        }
        const f32x4 accv = acc_h + acc_l;

        // C layout: col=lane&15 (unit), row=(lane>>4)*4+r (b'). -> Cx[gate][unit][b']
        #pragma unroll
        for (int r = 0; r < 4; ++r)
            Cx[wv][lane & 15][((lane >> 4) << 2) + r] = accv[r];
        __syncthreads();

        // ---- gate phase: thread (du, bp)
        const float ai = Cx[0][du][bp] + bf2f(x0);
        const float af = Cx[1][du][bp] + bf2f(x1);
        const float ao = Cx[2][du][bp] + bf2f(x2);
        const float ag = Cx[3][du][bp] + bf2f(x3);
        const float ig = sigmoidf_(ai);
        const float fg = sigmoidf_(af);
        const float og = sigmoidf_(ao);
        const float gg = tanhf_(ag);
        creg = fg * creg + ig * gg;
        const float hnew = og * tanhf_(creg);

        // publish h(t+1) (frag order, hi+lo, write-through)
        {
            const u16 hi = f2bf(hnew);
            const u16 lo = f2bf(hnew - bf2f(hi));
            u16* dst = hG + ((size_t)((t + 1) & 1) * 4 + i) * 2 * 8192;
            const int fa = fragaddr(u, bp);
            __hip_atomic_store(&dst[fa], hi, __ATOMIC_RELAXED, __HIP_MEMORY_SCOPE_AGENT);
            __hip_atomic_store(&dst[8192 + fa], lo, __ATOMIC_RELAXED, __HIP_MEMORY_SCOPE_AGENT);
        }
        hT[tid] = hnew;   // hT[du*16+bp]
        __syncthreads();  // publish stores drained in every wave + hT visible

        if (tid == 0)
            __hip_atomic_store(&flg[(i << 5) + j], (u32)(t + 2), __ATOMIC_RELEASE,
                               __HIP_MEMORY_SCOPE_AGENT);

        if (wv == 0) {    // out[b][t][16j+qd*4 .. +4]
            const int bq = lane >> 2;
            const int qd = lane & 3;
            float4 o4;
            o4.x = hT[(qd * 4 + 0) * 16 + bq];
            o4.y = hT[(qd * 4 + 1) * 16 + bq];
            o4.z = hT[(qd * 4 + 2) * 16 + bq];
            o4.w = hT[(qd * 4 + 3) * 16 + bq];
            *(float4*)(out + ((size_t)(16 * i + bq) * TSTEPS + t) * DK + 16 * j + qd * 4) = o4;
        }
    }
}

// ---------------------------------------------------------------------------
extern "C" void kernel_launch(void* const* d_in, const int* in_sizes, int n_in,
                              void* d_out, int out_size, void* d_ws, size_t ws_size,
                              hipStream_t stream) {
    const float* x    = (const float*)d_in[0];
    const float* h0   = (const float*)d_in[1];
    const float* Wx   = (const float*)d_in[2];
    const float* Wh   = (const float*)d_in[3];
    const float* bias = (const float*)d_in[4];
    float* out = (float*)d_out;

    u16* xw = (u16*)d_ws;
    const size_t XW_BYTES = (size_t)TSTEPS * NC * 64 * sizeof(u16);   // 134217728
    u16* hG  = (u16*)((char*)d_ws + XW_BYTES);                        // 256 KB
    u32* flg = (u32*)((char*)d_ws + XW_BYTES + 262144);               // 4x32 u32, line-aligned
    const size_t need = XW_BYTES + 262144 + 512;

    if (ws_size >= need) {
        dim3 g1(TSTEPS, 32);
        gemm_xwt<<<g1, 256, 0, stream>>>(x, Wx, bias, xw);
        init_flg<<<1, 128, 0, stream>>>(flg);
        lstm_rec5<<<128, 256, 0, stream>>>(xw, Wh, h0, out, hG, flg);
    } else {
        dim3 g1(512, 32);
        gemm_xw<<<g1, 256, 0, stream>>>(x, Wx, bias, xw);
        lstm_rec_old<<<64, 512, 0, stream>>>(xw, Wh, h0, out);
    }
}